// Round 14
// baseline (116.009 us; speedup 1.0000x reference)
//
#include <hip/hip_runtime.h>
#include <hip/hip_bf16.h>
#include <cstdint>

typedef unsigned int u32;
typedef __attribute__((ext_vector_type(8))) __bf16 bf16x8;
typedef __attribute__((ext_vector_type(4))) float f32x4;
typedef __attribute__((ext_vector_type(2))) _Float16 half2_t;
typedef __attribute__((ext_vector_type(4))) _Float16 half4;
typedef __attribute__((ext_vector_type(2))) __fp16 fp16x2;

#define BT_N 256
#define F_N 256
#define C_N 256
#define H_N 4
#define D_N 64
#define TC_N 768
#define M_N (BT_N * F_N)   // 65536
#define VT_ST 268          // vt row stride (halves)

__device__ __forceinline__ ushort f2bf(float f) {
  u32 u = __float_as_uint(f);
  u32 r = (u + 0x7fffu + ((u >> 16) & 1u)) >> 16;
  return (ushort)r;
}

__device__ __forceinline__ u32 pkbf(float a, float b) {
  return (u32)f2bf(a) | ((u32)f2bf(b) << 16);
}

__device__ __forceinline__ void gload_lds16(const ushort* g, ushort* l) {
  __builtin_amdgcn_global_load_lds(
      (const __attribute__((address_space(1))) u32*)g,
      (__attribute__((address_space(3))) u32*)l, 16, 0, 0);
}

// counted-vmcnt sync (T4)
#define WAITV(N) asm volatile("s_waitcnt vmcnt(" #N ")" ::: "memory")
#define BAR_IN  { __builtin_amdgcn_s_barrier(); \
                  asm volatile("" ::: "memory"); \
                  __builtin_amdgcn_sched_barrier(0); }
#define BAR_OUT { __builtin_amdgcn_sched_barrier(0); \
                  asm volatile("" ::: "memory"); \
                  __builtin_amdgcn_s_barrier(); }

// ---------------------------------------------------------------------------
// fp32 -> bf16 conversion (weights only)
// ---------------------------------------------------------------------------
__global__ __launch_bounds__(256) void cvt2_f32_bf16_k(
    const float* __restrict__ s0, ushort* __restrict__ d0, int n0,
    const float* __restrict__ s1, ushort* __restrict__ d1, int n1) {
  int idx = blockIdx.x * 256 + threadIdx.x;
  int stride = gridDim.x * 256;
  for (int i = idx; i < n0 + n1; i += stride) {
    const float4* s = (i < n0) ? ((const float4*)s0 + i) : ((const float4*)s1 + (i - n0));
    ushort* d = (i < n0) ? (d0 + (size_t)i * 4) : (d1 + (size_t)(i - n0) * 4);
    float4 v = *s;
    *(uint2*)d = make_uint2(pkbf(v.x, v.y), pkbf(v.z, v.w));
  }
}

// ---------------------------------------------------------------------------
// GEMM1 (qkv projection), A-in-registers, WIDE steps (32 MFMA/wave/step).
// Block = 64 M-rows x all N=768, K=256.  256 threads (4 waves: 2M x 2N).
// Step = N=256 x K=64 B-panel (32KB, dbuf 64KB): 12 steps total.
// Per step: STAGE next panel (8 gload_lds/thr), vmcnt(8), barrier,
// 32 MFMA, [epilogue at kt==3], barrier.  A never in LDS; C^T direct stores.
// ---------------------------------------------------------------------------
__global__ __launch_bounds__(256) void gemm_qkv(
    const float* __restrict__ x, const ushort* __restrict__ wb,
    const float* __restrict__ bias, _Float16* __restrict__ qkv, int nwg8) {
  __shared__ ushort Bs[2][256 * 64];   // [buf][row(panel N=256)][64 halves]

  const int tid = threadIdx.x;
  const int lane = tid & 63;
  const int wid = tid >> 6;
  const int wr = wid >> 1, wc = wid & 1;
  const int l15 = lane & 15, g = lane >> 4;
  const int b = blockIdx.x;
  const int bid = (b & 7) * nwg8 + (b >> 3);   // XCD swizzle (1024 % 8 == 0)
  const int rowBase = bid * 64;

  // ---- A fragments from global fp32, cvt in-reg ----
  bf16x8 af[2][8];  // [i2][ks]  (ks = kt*2+kk; k = ks*32 + g*8)
#pragma unroll
  for (int i2 = 0; i2 < 2; ++i2) {
    const float* xr = x + (size_t)(rowBase + wr * 32 + i2 * 16 + l15) * 256 + g * 8;
#pragma unroll
    for (int ks = 0; ks < 8; ++ks) {
      float4 f0 = *(const float4*)(xr + ks * 32);
      float4 f1 = *(const float4*)(xr + ks * 32 + 4);
      uint4 pk = make_uint4(pkbf(f0.x, f0.y), pkbf(f0.z, f0.w),
                            pkbf(f1.x, f1.y), pkbf(f1.z, f1.w));
      af[i2][ks] = __builtin_bit_cast(bf16x8, pk);
    }
  }

  const int sr = tid >> 3;        // row low bits (0..31)
  const int sc = tid & 7;         // chunk 0..7
  const int scs = sc ^ (sr & 7);  // pre-swizzled source chunk (loop-invariant)
#define STAGE_B(buf, nt2, kt)                                                 \
  {                                                                           \
    ushort* B_ = Bs[buf];                                                     \
    _Pragma("unroll") for (int p = 0; p < 8; ++p) {                           \
      int r = p * 32 + sr;                                                    \
      const ushort* gb = wb + (size_t)((nt2) * 256 + r) * 256 + (kt) * 64 +   \
                         (scs << 3);                                          \
      gload_lds16(gb, B_ + (size_t)(p * 256 + tid) * 8);                      \
    }                                                                         \
  }

  f32x4 acc[2][8] = {};
  STAGE_B(0, 0, 0);

#pragma unroll
  for (int nt2 = 0; nt2 < 3; ++nt2) {
#pragma unroll
    for (int kt = 0; kt < 4; ++kt) {
      const int s = nt2 * 4 + kt;
      if (s < 11) {
        const int nx = (s + 1) >> 2, kx = (s + 1) & 3;
        STAGE_B((s + 1) & 1, nx, kx);
        WAITV(8);                 // current panel landed; next stays in flight
      } else {
        WAITV(0);
      }
      BAR_IN;
      const ushort* B_ = Bs[s & 1];
#pragma unroll
      for (int kk = 0; kk < 2; ++kk) {
        bf16x8 bfr[8];
#pragma unroll
        for (int j2 = 0; j2 < 8; ++j2) {
          int rp = wc * 128 + j2 * 16 + l15;   // panel row (0..255)
          bfr[j2] = *(const bf16x8*)(B_ + rp * 64 + (((kk * 4 + g) ^ (l15 & 7)) * 8));
        }
#pragma unroll
        for (int i2 = 0; i2 < 2; ++i2)
#pragma unroll
          for (int j2 = 0; j2 < 8; ++j2)
            acc[i2][j2] = __builtin_amdgcn_mfma_f32_16x16x32_bf16(
                bfr[j2], af[i2][kt * 2 + kk], acc[i2][j2], 0, 0, 0);
      }
      if (kt == 3) {
        // epilogue for this nt2: lane holds C[row][col..col+3] (C^T frag)
#pragma unroll
        for (int j2 = 0; j2 < 8; ++j2) {
          int col = nt2 * 256 + wc * 128 + j2 * 16 + g * 4;
          float4 bv = *(const float4*)(bias + col);
#pragma unroll
          for (int i2 = 0; i2 < 2; ++i2) {
            int row = rowBase + wr * 32 + i2 * 16 + l15;
            fp16x2 lo = __builtin_amdgcn_cvt_pkrtz(acc[i2][j2][0] + bv.x,
                                                   acc[i2][j2][1] + bv.y);
            fp16x2 hi = __builtin_amdgcn_cvt_pkrtz(acc[i2][j2][2] + bv.z,
                                                   acc[i2][j2][3] + bv.w);
            *(uint2*)(qkv + (size_t)row * 768 + col) =
                make_uint2(__builtin_bit_cast(u32, lo), __builtin_bit_cast(u32, hi));
            acc[i2][j2] = f32x4{0.f, 0.f, 0.f, 0.f};
          }
        }
      }
      BAR_OUT;
    }
  }
#undef STAGE_B
}

// ---------------------------------------------------------------------------
// GEMM2: y = attn @ w_out^T + b_out.  Counted-vmcnt pipeline (verbatim r13).
// ---------------------------------------------------------------------------
template <typename OutT>
__global__ __launch_bounds__(256, 2) void gemm_bt(
    const ushort* __restrict__ Ap, const ushort* __restrict__ Bp,
    const float* __restrict__ bias, OutT* __restrict__ Cp,
    int N, int NTN, int nwg8) {
  constexpr bool F32OUT = (sizeof(OutT) == 4);
  constexpr int SMEM_BYTES = F32OUT ? 67584 : 65536;
  __shared__ char smem[SMEM_BYTES];
  ushort* smemH = (ushort*)smem;

  const int tid = threadIdx.x;
  const int lane = tid & 63;
  const int wid = tid >> 6;
  const int wr = wid >> 1, wc = wid & 1;
  const int l15 = lane & 15, l4 = lane >> 4;
  const int b = blockIdx.x;
  const int bid = (b & 7) * nwg8 + (b >> 3);
  const int tm = bid / NTN;
  const int tn = bid - tm * NTN;
  const int rowBase = tm * 128, colBase = tn * 128;

  f32x4 acc[4][4] = {};

  const int ar = (tid >> 3);
  const int c8 = tid & 7;
  const int akk = ((c8 ^ (ar & 7)) << 3);
  const ushort* gB = Bp + (size_t)(colBase + ar) * 256 + akk;
  const ushort* gAh = Ap + (size_t)(rowBase + ar) * 256 + akk;

#define STAGE_AB(buf, k0)                                                     \
  {                                                                           \
    ushort* As_ = smemH + (buf) * 8192;                                       \
    ushort* Bs_ = smemH + 16384 + (buf) * 8192;                               \
    _Pragma("unroll") for (int c = 0; c < 4; ++c) {                           \
      gload_lds16(gAh + (size_t)(c * 32) * 256 + (k0),                        \
                  As_ + (size_t)(c * 256 + (wid << 6)) * 8);                  \
      gload_lds16(gB + (size_t)(c * 32) * 256 + (k0),                         \
                  Bs_ + (size_t)(c * 256 + (wid << 6)) * 8);                  \
    }                                                                         \
  }

  STAGE_AB(0, 0);

  int cur = 0;
#pragma unroll
  for (int t = 0; t < 4; ++t) {
    if (t < 3) {
      STAGE_AB(cur ^ 1, (t + 1) * 64);
      WAITV(8);
    } else {
      WAITV(0);
    }
    BAR_IN;
    const ushort* As_ = smemH + cur * 8192;
    const ushort* Bs_ = smemH + 16384 + cur * 8192;
#pragma unroll
    for (int kk = 0; kk < 2; ++kk) {
      bf16x8 af[4];
      bf16x8 bfr[4];
#pragma unroll
      for (int i2 = 0; i2 < 4; ++i2) {
        int row = wr * 64 + i2 * 16 + l15;
        af[i2] = *(const bf16x8*)(As_ + row * 64 + (((kk * 4 + l4) ^ (l15 & 7)) * 8));
      }
#pragma unroll
      for (int j2 = 0; j2 < 4; ++j2) {
        int row = wc * 64 + j2 * 16 + l15;
        bfr[j2] = *(const bf16x8*)(Bs_ + row * 64 + (((kk * 4 + l4) ^ (l15 & 7)) * 8));
      }
#pragma unroll
      for (int i2 = 0; i2 < 4; ++i2)
#pragma unroll
        for (int j2 = 0; j2 < 4; ++j2)
          acc[i2][j2] = __builtin_amdgcn_mfma_f32_16x16x32_bf16(
              af[i2], bfr[j2], acc[i2][j2], 0, 0, 0);
    }
    BAR_OUT;
    cur ^= 1;
  }
#undef STAGE_AB

  __syncthreads();
  if constexpr (F32OUT) {
    float* eb = (float*)smem;
#pragma unroll
    for (int j2 = 0; j2 < 4; ++j2) {
      float bv = bias[colBase + wc * 64 + j2 * 16 + l15];
#pragma unroll
      for (int i2 = 0; i2 < 4; ++i2)
#pragma unroll
        for (int r = 0; r < 4; ++r)
          eb[(wr * 64 + i2 * 16 + l4 * 4 + r) * 132 + wc * 64 + j2 * 16 + l15] =
              acc[i2][j2][r] + bv;
    }
    __syncthreads();
#pragma unroll
    for (int i = 0; i < 32; ++i) {
      int row = wid * 32 + i;
      uint2 d = *(const uint2*)((const u32*)eb + row * 132 + lane * 2);
      *(uint2*)((float*)Cp + (size_t)(rowBase + row) * N + colBase + lane * 2) = d;
    }
  } else {
    ushort* eb = smemH;
#pragma unroll
    for (int j2 = 0; j2 < 4; ++j2) {
      float bv = bias[colBase + wc * 64 + j2 * 16 + l15];
#pragma unroll
      for (int i2 = 0; i2 < 4; ++i2)
#pragma unroll
        for (int r = 0; r < 4; ++r) {
          _Float16 h = (_Float16)(acc[i2][j2][r] + bv);
          eb[(wr * 64 + i2 * 16 + l4 * 4 + r) * 136 + wc * 64 + j2 * 16 + l15] =
              __builtin_bit_cast(ushort, h);
        }
    }
    __syncthreads();
#pragma unroll
    for (int i = 0; i < 16; ++i) {
      int row = wid * 32 + 2 * i + (lane >> 5);
      int hl = lane & 31;
      uint2 d = *(const uint2*)(eb + row * 136 + hl * 4);
      *(uint2*)((_Float16*)Cp + (size_t)(rowBase + row) * N + colBase + hl * 4) = d;
    }
  }
}

// ---------------------------------------------------------------------------
// Banded attention via MFMA (verbatim — verified rounds 8-13).
// ---------------------------------------------------------------------------
__global__ __launch_bounds__(256) void attn_mfma(
    const _Float16* __restrict__ qkv, ushort* __restrict__ aout) {
  __shared__ ushort smem[18432 + 64 * VT_ST];
  const int tid = threadIdx.x;
  const int bt = blockIdx.x >> 2;
  const int h = blockIdx.x & 3;
  const _Float16* base = qkv + (size_t)bt * 256 * 768 + h * 64;
  ushort* klds = smem;
  ushort* vlds = smem + 18432;

  {
    const int r0 = tid >> 3, c8 = tid & 7;
#pragma unroll
    for (int p = 0; p < 8; ++p) {
      int j = p * 32 + r0;
      const uint4 k4 = *(const uint4*)(base + (size_t)j * 768 + 256 + c8 * 8);
      *(uint4*)(klds + j * 72 + c8 * 8) = k4;
      const uint4 v4 = *(const uint4*)(base + (size_t)j * 768 + 512 + c8 * 8);
      const ushort* vh = (const ushort*)&v4;
      ushort* vtp = vlds + (c8 * 8) * VT_ST + j;
#pragma unroll
      for (int i = 0; i < 8; ++i) vtp[i * VT_ST] = vh[i];
    }
  }

  const int w = tid >> 6, lane = tid & 63;
  const int l15 = lane & 15, g = lane >> 4, g4 = g * 4;

  uint2 qf0[4], qf1[4], qf2[4], qf3[4];
  {
    const uint2* q0 = (const uint2*)(base + (size_t)(w * 64 + 0 * 16 + l15) * 768 + g4);
    const uint2* q1 = (const uint2*)(base + (size_t)(w * 64 + 1 * 16 + l15) * 768 + g4);
    const uint2* q2 = (const uint2*)(base + (size_t)(w * 64 + 2 * 16 + l15) * 768 + g4);
    const uint2* q3 = (const uint2*)(base + (size_t)(w * 64 + 3 * 16 + l15) * 768 + g4);
#pragma unroll
    for (int ks = 0; ks < 4; ++ks) {
      qf0[ks] = q0[ks * 4]; qf1[ks] = q1[ks * 4];
      qf2[ks] = q2[ks * 4]; qf3[ks] = q3[ks * 4];
    }
  }

  u32 bb = 0;
#pragma unroll
  for (int jt = 0; jt < 3; ++jt)
#pragma unroll
    for (int r = 0; r < 4; ++r) {
      int d = 16 * jt + g4 + r - 16 - l15;
      if (d >= -16 && d <= 16) bb |= 1u << (jt * 4 + r);
    }

  __syncthreads();

  const float SC = 0.18033688f;  // 0.125 * log2(e)

#pragma unroll
  for (int rt = 0; rt < 4; ++rt) {
    const int R0 = w * 64 + rt * 16;
    const int Jc = R0 - 16;
    const uint2* qf = (rt == 0) ? qf0 : (rt == 1) ? qf1 : (rt == 2) ? qf2 : qf3;

    f32x4 st[3] = {};
#pragma unroll
    for (int jt = 0; jt < 3; ++jt) {
      int krow = Jc + 16 * jt + l15;
      krow = krow < 0 ? 0 : (krow > 255 ? 255 : krow);
      const ushort* kp = klds + krow * 72 + g4;
#pragma unroll
      for (int ks = 0; ks < 4; ++ks) {
        uint2 kf = *(const uint2*)(kp + ks * 16);
        st[jt] = __builtin_amdgcn_mfma_f32_16x16x16f16(
            __builtin_bit_cast(half4, kf), __builtin_bit_cast(half4, qf[ks]),
            st[jt], 0, 0, 0);
      }
    }

    float l_acc = 0.f;
    float pp[3][4];
#pragma unroll
    for (int jt = 0; jt < 3; ++jt)
#pragma unroll
      for (int r = 0; r < 4; ++r) {
        int jg = Jc + 16 * jt + g4 + r;
        bool keep = (((bb >> (jt * 4 + r)) & 1u) != 0) && (jg >= 0) && (jg < 256);
        float pv = keep ? __builtin_amdgcn_exp2f(st[jt][r] * SC) : 0.f;
        pp[jt][r] = pv;
        l_acc += pv;
      }
    l_acc += __shfl_xor(l_acc, 16, 64);
    l_acc += __shfl_xor(l_acc, 32, 64);
    const float inv = 1.f / l_acc;

    uint2 pf[3];
#pragma unroll
    for (int jt = 0; jt < 3; ++jt) {
      fp16x2 a = __builtin_amdgcn_cvt_pkrtz(pp[jt][0] * inv, pp[jt][1] * inv);
      fp16x2 c = __builtin_amdgcn_cvt_pkrtz(pp[jt][2] * inv, pp[jt][3] * inv);
      pf[jt].x = __builtin_bit_cast(u32, a);
      pf[jt].y = __builtin_bit_cast(u32, c);
    }

    f32x4 ot[4] = {};
#pragma unroll
    for (int kt = 0; kt < 3; ++kt) {
      int jb = Jc + 16 * kt + g4;
      jb = jb < 0 ? 0 : (jb > 252 ? 252 : jb);
#pragma unroll
      for (int mt = 0; mt < 4; ++mt) {
        uint2 vfr = *(const uint2*)(vlds + (16 * mt + l15) * VT_ST + jb);
        ot[mt] = __builtin_amdgcn_mfma_f32_16x16x16f16(
            __builtin_bit_cast(half4, vfr), __builtin_bit_cast(half4, pf[kt]),
            ot[mt], 0, 0, 0);
      }
    }

    ushort* orow = aout + (size_t)(bt * 256 + R0 + l15) * 256 + h * 64 + g4;
#pragma unroll
    for (int mt = 0; mt < 4; ++mt) {
      u32 lo = (u32)f2bf(ot[mt][0]) | ((u32)f2bf(ot[mt][1]) << 16);
      u32 hi = (u32)f2bf(ot[mt][2]) | ((u32)f2bf(ot[mt][3]) << 16);
      *(uint2*)(orow + mt * 16) = make_uint2(lo, hi);
    }
  }
}

// ---------------------------------------------------------------------------
extern "C" void kernel_launch(void* const* d_in, const int* in_sizes, int n_in,
                              void* d_out, int out_size, void* d_ws, size_t ws_size,
                              hipStream_t stream) {
  const float* x = (const float*)d_in[0];
  const float* w_in = (const float*)d_in[1];
  const float* b_in = (const float*)d_in[2];
  const float* w_out = (const float*)d_in[3];
  const float* b_out = (const float*)d_in[4];
  float* y = (float*)d_out;

  char* ws = (char*)d_ws;
  const size_t qkv_bytes = (size_t)M_N * TC_N * 2;
  _Float16* qkv = (_Float16*)ws;
  ushort* attn = (ushort*)(ws + qkv_bytes);
  ushort* winb = attn + (size_t)M_N * C_N;
  ushort* woutb = winb + TC_N * C_N;

  // weights fp32 -> bf16 (tiny)
  cvt2_f32_bf16_k<<<256, 256, 0, stream>>>(w_in, winb, TC_N * C_N / 4,
                                           w_out, woutb, C_N * C_N / 4);

  // qkv = x @ w_in^T + b_in  (A-in-registers from fp32 x; f16 out)
  gemm_qkv<<<M_N / 64, 256, 0, stream>>>(x, winb, b_in, qkv, (M_N / 64) / 8);

  // banded attention (bf16 out)
  attn_mfma<<<BT_N * H_N, 256, 0, stream>>>(qkv, attn);

  // y = attn @ w_out^T + b_out  (fp32 out)
  gemm_bt<float><<<(M_N / 128) * (C_N / 128), 256, 0, stream>>>(
      attn, woutb, b_out, y, C_N, C_N / 128, (M_N / 128) * (C_N / 128) / 8);
}

// Round 15
// 105.768 us; speedup vs baseline: 1.0968x; 1.0968x over previous
//
#include <hip/hip_runtime.h>
#include <hip/hip_bf16.h>
#include <cstdint>

typedef unsigned int u32;
typedef __attribute__((ext_vector_type(8))) __bf16 bf16x8;
typedef __attribute__((ext_vector_type(4))) float f32x4;
typedef __attribute__((ext_vector_type(2))) _Float16 half2_t;
typedef __attribute__((ext_vector_type(4))) _Float16 half4;
typedef __attribute__((ext_vector_type(2))) __fp16 fp16x2;

#define BT_N 256
#define F_N 256
#define C_N 256
#define H_N 4
#define D_N 64
#define TC_N 768
#define M_N (BT_N * F_N)   // 65536
#define VT_ST 268          // vt row stride (halves)

__device__ __forceinline__ ushort f2bf(float f) {
  u32 u = __float_as_uint(f);
  u32 r = (u + 0x7fffu + ((u >> 16) & 1u)) >> 16;
  return (ushort)r;
}

__device__ __forceinline__ u32 pkbf(float a, float b) {
  return (u32)f2bf(a) | ((u32)f2bf(b) << 16);
}

__device__ __forceinline__ void gload_lds16(const ushort* g, ushort* l) {
  __builtin_amdgcn_global_load_lds(
      (const __attribute__((address_space(1))) u32*)g,
      (__attribute__((address_space(3))) u32*)l, 16, 0, 0);
}

// counted-vmcnt sync (T4): next-tile loads stay in flight across barrier.
#define WAITV(N) asm volatile("s_waitcnt vmcnt(" #N ")" ::: "memory")
#define BAR_IN  { __builtin_amdgcn_s_barrier(); \
                  asm volatile("" ::: "memory"); \
                  __builtin_amdgcn_sched_barrier(0); }
#define BAR_OUT { __builtin_amdgcn_sched_barrier(0); \
                  asm volatile("" ::: "memory"); \
                  __builtin_amdgcn_s_barrier(); }

// ---------------------------------------------------------------------------
// fp32 -> bf16 conversion: x, w_in, w_out in ONE launch (r9-verified)
// ---------------------------------------------------------------------------
__global__ __launch_bounds__(256) void cvt3_f32_bf16_k(
    const float* __restrict__ sx, ushort* __restrict__ dx, int nx4,
    const float* __restrict__ si, ushort* __restrict__ di, int ni4,
    const float* __restrict__ so, ushort* __restrict__ dq, int no4) {
  int idx = blockIdx.x * 256 + threadIdx.x;
  int stride = gridDim.x * 256;
  int ntot = nx4 + ni4 + no4;
  for (int i = idx; i < ntot; i += stride) {
    const float4* s;
    ushort* d;
    if (i < nx4) { s = (const float4*)sx + i; d = dx + (size_t)i * 4; }
    else if (i < nx4 + ni4) { int k = i - nx4; s = (const float4*)si + k; d = di + (size_t)k * 4; }
    else { int k = i - nx4 - ni4; s = (const float4*)so + k; d = dq + (size_t)k * 4; }
    float4 v = *s;
    *(uint2*)d = make_uint2(pkbf(v.x, v.y), pkbf(v.z, v.w));
  }
}

// ---------------------------------------------------------------------------
// GEMM: C[m][n] = sum_k A[m][k]*B[n][k] + bias[n].  K=256 fixed.
// r9 structure (45.5us GEMM1): A,B bf16 via global_load_lds, chunk-XOR
// swizzle, 128x128 tile, BK=64, dbuf; delta vs r9: counted-vmcnt two-barrier
// K-loop (r13-validated).  Epilogue via LDS, strictly post-loop.
// ---------------------------------------------------------------------------
template <typename OutT>
__global__ __launch_bounds__(256, 2) void gemm_bt(
    const ushort* __restrict__ Ap, const ushort* __restrict__ Bp,
    const float* __restrict__ bias, OutT* __restrict__ Cp,
    int N, int NTN, int nwg8) {
  constexpr bool F32OUT = (sizeof(OutT) == 4);
  constexpr int SMEM_BYTES = F32OUT ? 67584 : 65536;
  __shared__ char smem[SMEM_BYTES];
  ushort* smemH = (ushort*)smem;

  const int tid = threadIdx.x;
  const int lane = tid & 63;
  const int wid = tid >> 6;
  const int wr = wid >> 1, wc = wid & 1;
  const int l15 = lane & 15, l4 = lane >> 4;
  const int b = blockIdx.x;
  const int bid = (b & 7) * nwg8 + (b >> 3);
  const int tm = bid / NTN;
  const int tn = bid - tm * NTN;
  const int rowBase = tm * 128, colBase = tn * 128;

  f32x4 acc[4][4] = {};

  const int ar = (tid >> 3);
  const int c8 = tid & 7;
  const int akk = ((c8 ^ (ar & 7)) << 3);
  const ushort* gB = Bp + (size_t)(colBase + ar) * 256 + akk;
  const ushort* gAh = Ap + (size_t)(rowBase + ar) * 256 + akk;

#define STAGE_AB(buf, k0)                                                     \
  {                                                                           \
    ushort* As_ = smemH + (buf) * 8192;                                       \
    ushort* Bs_ = smemH + 16384 + (buf) * 8192;                               \
    _Pragma("unroll") for (int c = 0; c < 4; ++c) {                           \
      gload_lds16(gAh + (size_t)(c * 32) * 256 + (k0),                        \
                  As_ + (size_t)(c * 256 + (wid << 6)) * 8);                  \
      gload_lds16(gB + (size_t)(c * 32) * 256 + (k0),                         \
                  Bs_ + (size_t)(c * 256 + (wid << 6)) * 8);                  \
    }                                                                         \
  }

  STAGE_AB(0, 0);

  int cur = 0;
#pragma unroll
  for (int t = 0; t < 4; ++t) {
    if (t < 3) {
      STAGE_AB(cur ^ 1, (t + 1) * 64);
      WAITV(8);                   // tile t landed; tile t+1 stays in flight
    } else {
      WAITV(0);
    }
    BAR_IN;
    const ushort* As_ = smemH + cur * 8192;
    const ushort* Bs_ = smemH + 16384 + cur * 8192;
#pragma unroll
    for (int kk = 0; kk < 2; ++kk) {
      bf16x8 af[4];
      bf16x8 bfr[4];
#pragma unroll
      for (int i2 = 0; i2 < 4; ++i2) {
        int row = wr * 64 + i2 * 16 + l15;
        af[i2] = *(const bf16x8*)(As_ + row * 64 + (((kk * 4 + l4) ^ (l15 & 7)) * 8));
      }
#pragma unroll
      for (int j2 = 0; j2 < 4; ++j2) {
        int row = wc * 64 + j2 * 16 + l15;
        bfr[j2] = *(const bf16x8*)(Bs_ + row * 64 + (((kk * 4 + l4) ^ (l15 & 7)) * 8));
      }
#pragma unroll
      for (int i2 = 0; i2 < 4; ++i2)
#pragma unroll
        for (int j2 = 0; j2 < 4; ++j2)
          acc[i2][j2] = __builtin_amdgcn_mfma_f32_16x16x32_bf16(
              af[i2], bfr[j2], acc[i2][j2], 0, 0, 0);
    }
    BAR_OUT;
    cur ^= 1;
  }
#undef STAGE_AB

  // ---- epilogue via LDS (coalesced stores), strictly post-loop ----
  __syncthreads();
  if constexpr (F32OUT) {
    float* eb = (float*)smem;
#pragma unroll
    for (int j2 = 0; j2 < 4; ++j2) {
      float bv = bias[colBase + wc * 64 + j2 * 16 + l15];
#pragma unroll
      for (int i2 = 0; i2 < 4; ++i2)
#pragma unroll
        for (int r = 0; r < 4; ++r)
          eb[(wr * 64 + i2 * 16 + l4 * 4 + r) * 132 + wc * 64 + j2 * 16 + l15] =
              acc[i2][j2][r] + bv;
    }
    __syncthreads();
#pragma unroll
    for (int i = 0; i < 32; ++i) {
      int row = wid * 32 + i;
      uint2 d = *(const uint2*)((const u32*)eb + row * 132 + lane * 2);
      *(uint2*)((float*)Cp + (size_t)(rowBase + row) * N + colBase + lane * 2) = d;
    }
  } else {
    ushort* eb = smemH;
#pragma unroll
    for (int j2 = 0; j2 < 4; ++j2) {
      float bv = bias[colBase + wc * 64 + j2 * 16 + l15];
#pragma unroll
      for (int i2 = 0; i2 < 4; ++i2)
#pragma unroll
        for (int r = 0; r < 4; ++r) {
          _Float16 h = (_Float16)(acc[i2][j2][r] + bv);
          eb[(wr * 64 + i2 * 16 + l4 * 4 + r) * 136 + wc * 64 + j2 * 16 + l15] =
              __builtin_bit_cast(ushort, h);
        }
    }
    __syncthreads();
#pragma unroll
    for (int i = 0; i < 16; ++i) {
      int row = wid * 32 + 2 * i + (lane >> 5);
      int hl = lane & 31;
      uint2 d = *(const uint2*)(eb + row * 136 + hl * 4);
      *(uint2*)((_Float16*)Cp + (size_t)(rowBase + row) * N + colBase + hl * 4) = d;
    }
  }
}

// ---------------------------------------------------------------------------
// Banded attention via MFMA (verbatim — verified rounds 8-14).
// ---------------------------------------------------------------------------
__global__ __launch_bounds__(256) void attn_mfma(
    const _Float16* __restrict__ qkv, ushort* __restrict__ aout) {
  __shared__ ushort smem[18432 + 64 * VT_ST];
  const int tid = threadIdx.x;
  const int bt = blockIdx.x >> 2;
  const int h = blockIdx.x & 3;
  const _Float16* base = qkv + (size_t)bt * 256 * 768 + h * 64;
  ushort* klds = smem;
  ushort* vlds = smem + 18432;

  {
    const int r0 = tid >> 3, c8 = tid & 7;
#pragma unroll
    for (int p = 0; p < 8; ++p) {
      int j = p * 32 + r0;
      const uint4 k4 = *(const uint4*)(base + (size_t)j * 768 + 256 + c8 * 8);
      *(uint4*)(klds + j * 72 + c8 * 8) = k4;
      const uint4 v4 = *(const uint4*)(base + (size_t)j * 768 + 512 + c8 * 8);
      const ushort* vh = (const ushort*)&v4;
      ushort* vtp = vlds + (c8 * 8) * VT_ST + j;
#pragma unroll
      for (int i = 0; i < 8; ++i) vtp[i * VT_ST] = vh[i];
    }
  }

  const int w = tid >> 6, lane = tid & 63;
  const int l15 = lane & 15, g = lane >> 4, g4 = g * 4;

  uint2 qf0[4], qf1[4], qf2[4], qf3[4];
  {
    const uint2* q0 = (const uint2*)(base + (size_t)(w * 64 + 0 * 16 + l15) * 768 + g4);
    const uint2* q1 = (const uint2*)(base + (size_t)(w * 64 + 1 * 16 + l15) * 768 + g4);
    const uint2* q2 = (const uint2*)(base + (size_t)(w * 64 + 2 * 16 + l15) * 768 + g4);
    const uint2* q3 = (const uint2*)(base + (size_t)(w * 64 + 3 * 16 + l15) * 768 + g4);
#pragma unroll
    for (int ks = 0; ks < 4; ++ks) {
      qf0[ks] = q0[ks * 4]; qf1[ks] = q1[ks * 4];
      qf2[ks] = q2[ks * 4]; qf3[ks] = q3[ks * 4];
    }
  }

  u32 bb = 0;
#pragma unroll
  for (int jt = 0; jt < 3; ++jt)
#pragma unroll
    for (int r = 0; r < 4; ++r) {
      int d = 16 * jt + g4 + r - 16 - l15;
      if (d >= -16 && d <= 16) bb |= 1u << (jt * 4 + r);
    }

  __syncthreads();

  const float SC = 0.18033688f;  // 0.125 * log2(e)

#pragma unroll
  for (int rt = 0; rt < 4; ++rt) {
    const int R0 = w * 64 + rt * 16;
    const int Jc = R0 - 16;
    const uint2* qf = (rt == 0) ? qf0 : (rt == 1) ? qf1 : (rt == 2) ? qf2 : qf3;

    f32x4 st[3] = {};
#pragma unroll
    for (int jt = 0; jt < 3; ++jt) {
      int krow = Jc + 16 * jt + l15;
      krow = krow < 0 ? 0 : (krow > 255 ? 255 : krow);
      const ushort* kp = klds + krow * 72 + g4;
#pragma unroll
      for (int ks = 0; ks < 4; ++ks) {
        uint2 kf = *(const uint2*)(kp + ks * 16);
        st[jt] = __builtin_amdgcn_mfma_f32_16x16x16f16(
            __builtin_bit_cast(half4, kf), __builtin_bit_cast(half4, qf[ks]),
            st[jt], 0, 0, 0);
      }
    }

    float l_acc = 0.f;
    float pp[3][4];
#pragma unroll
    for (int jt = 0; jt < 3; ++jt)
#pragma unroll
      for (int r = 0; r < 4; ++r) {
        int jg = Jc + 16 * jt + g4 + r;
        bool keep = (((bb >> (jt * 4 + r)) & 1u) != 0) && (jg >= 0) && (jg < 256);
        float pv = keep ? __builtin_amdgcn_exp2f(st[jt][r] * SC) : 0.f;
        pp[jt][r] = pv;
        l_acc += pv;
      }
    l_acc += __shfl_xor(l_acc, 16, 64);
    l_acc += __shfl_xor(l_acc, 32, 64);
    const float inv = 1.f / l_acc;

    uint2 pf[3];
#pragma unroll
    for (int jt = 0; jt < 3; ++jt) {
      fp16x2 a = __builtin_amdgcn_cvt_pkrtz(pp[jt][0] * inv, pp[jt][1] * inv);
      fp16x2 c = __builtin_amdgcn_cvt_pkrtz(pp[jt][2] * inv, pp[jt][3] * inv);
      pf[jt].x = __builtin_bit_cast(u32, a);
      pf[jt].y = __builtin_bit_cast(u32, c);
    }

    f32x4 ot[4] = {};
#pragma unroll
    for (int kt = 0; kt < 3; ++kt) {
      int jb = Jc + 16 * kt + g4;
      jb = jb < 0 ? 0 : (jb > 252 ? 252 : jb);
#pragma unroll
      for (int mt = 0; mt < 4; ++mt) {
        uint2 vfr = *(const uint2*)(vlds + (16 * mt + l15) * VT_ST + jb);
        ot[mt] = __builtin_amdgcn_mfma_f32_16x16x16f16(
            __builtin_bit_cast(half4, vfr), __builtin_bit_cast(half4, pf[kt]),
            ot[mt], 0, 0, 0);
      }
    }

    ushort* orow = aout + (size_t)(bt * 256 + R0 + l15) * 256 + h * 64 + g4;
#pragma unroll
    for (int mt = 0; mt < 4; ++mt) {
      u32 lo = (u32)f2bf(ot[mt][0]) | ((u32)f2bf(ot[mt][1]) << 16);
      u32 hi = (u32)f2bf(ot[mt][2]) | ((u32)f2bf(ot[mt][3]) << 16);
      *(uint2*)(orow + mt * 16) = make_uint2(lo, hi);
    }
  }
}

// ---------------------------------------------------------------------------
extern "C" void kernel_launch(void* const* d_in, const int* in_sizes, int n_in,
                              void* d_out, int out_size, void* d_ws, size_t ws_size,
                              hipStream_t stream) {
  const float* x = (const float*)d_in[0];
  const float* w_in = (const float*)d_in[1];
  const float* b_in = (const float*)d_in[2];
  const float* w_out = (const float*)d_in[3];
  const float* b_out = (const float*)d_in[4];
  float* y = (float*)d_out;

  char* ws = (char*)d_ws;
  const size_t qkv_bytes = (size_t)M_N * TC_N * 2;
  const size_t xb_bytes = (size_t)M_N * C_N * 2;
  _Float16* qkv = (_Float16*)ws;
  ushort* xb = (ushort*)(ws + qkv_bytes);
  ushort* attn = xb;  // aliased: xb dead after gemm1
  ushort* winb = (ushort*)(ws + qkv_bytes + xb_bytes);
  ushort* woutb = winb + TC_N * C_N;

  // x + weights fp32 -> bf16 (single launch)
  cvt3_f32_bf16_k<<<2048, 256, 0, stream>>>(x, xb, M_N * C_N / 4,
                                            w_in, winb, TC_N * C_N / 4,
                                            w_out, woutb, C_N * C_N / 4);

  // qkv = x @ w_in^T + b_in  (f16 out)
  gemm_bt<_Float16><<<(M_N / 128) * (TC_N / 128), 256, 0, stream>>>(
      xb, winb, b_in, qkv, TC_N, TC_N / 128, (M_N / 128) * (TC_N / 128) / 8);

  // banded attention (bf16 out)
  attn_mfma<<<BT_N * H_N, 256, 0, stream>>>(qkv, attn);

  // y = attn @ w_out^T + b_out  (fp32 out)
  gemm_bt<float><<<(M_N / 128) * (C_N / 128), 256, 0, stream>>>(
      attn, woutb, b_out, y, C_N, C_N / 128, (M_N / 128) * (C_N / 128) / 8);
}